// Round 12
// baseline (2276.141 us; speedup 1.0000x reference)
//
#include <hip/hip_runtime.h>
#include <math.h>

// ---------------------------------------------------------------------------
// R12: R11 stayed at 770us/ODE (same as R7/R8) with VALUBusy=102% -> the
// x-broadcast ds_read_b128s were the hidden cost (same-addr b128 charges
// full LDS BW: ~8cy x 64/feval4 = 512cy; broadcast shortcut is b32-only).
// Fix: broadcast x via v_readlane -> SGPR (index q*4+u is wave-uniform),
// feeding v_fma's one-SGPR-operand slot. LDS now carries ONLY the weight
// stream (256cy/feval4, ~50us equiv). xbuf + ds_writes deleted.
// Convs/BN unchanged (pass, absmax 0.03125).
// ---------------------------------------------------------------------------

#define NELEM (16 * 64 * 64 * 64)  // 4194304, B*C*H*W with C=64

__device__ float  g_y1f[NELEM];   // conv1 out -> overwritten in-place by spike1
__device__ float  g_yscf[NELEM];  // 1x1 shortcut conv out
__device__ float  g_y2f[NELEM];   // conv2 out
__device__ double g_part[384][1024];  // per-block stat partials (f64)
__device__ double g_stats[384];
__device__ double g_prm[384];     // [0]=bn1 sc,[64]=bn1 sh,[128]=sc sc,[192]=sc sh,
                                  // [256]=bn2 sc,[320]=bn2 sh

__device__ __forceinline__ double wave_sum64(double v) {
#pragma unroll
  for (int m = 1; m < 64; m <<= 1) v += __shfl_xor(v, m);
  return v;
}

__device__ __forceinline__ float bcast_f(float v, int l) {
  return __uint_as_float(__builtin_amdgcn_readlane(__float_as_uint(v), l));
}

// ---------------- conv1 (3x3, 32->64, bias, f32) + sc conv (1x1) ------------
__global__ __launch_bounds__(256) void conv1_sc_kernel(
    const float* __restrict__ x, const float* __restrict__ w1,
    const float* __restrict__ b1, const float* __restrict__ scw)
{
  const int b = blockIdx.x >> 6, h = blockIdx.x & 63;
  const int w = threadIdx.x & 63;
  const int cog = __builtin_amdgcn_readfirstlane(threadIdx.x >> 6);  // 0..3
  __shared__ float xs[3][32][64];
  for (int i = threadIdx.x; i < 3 * 32 * 64; i += 256) {
    int kh = i >> 11, ci = (i >> 6) & 31, ww = i & 63;
    int hh = h + kh - 1;
    xs[kh][ci][ww] = ((unsigned)hh < 64u) ? x[((b * 32 + ci) << 12) + (hh << 6) + ww] : 0.f;
  }
  __syncthreads();

  float acc[16], asc[16];
#pragma unroll
  for (int i = 0; i < 16; ++i) { acc[i] = b1[cog * 16 + i]; asc[i] = 0.f; }

  for (int ci = 0; ci < 32; ++ci) {
    float xv[3][3];
#pragma unroll
    for (int kh = 0; kh < 3; ++kh) {
      xv[kh][0] = (w > 0)  ? xs[kh][ci][w - 1] : 0.f;
      xv[kh][1] = xs[kh][ci][w];
      xv[kh][2] = (w < 63) ? xs[kh][ci][w + 1] : 0.f;
    }
#pragma unroll
    for (int i = 0; i < 16; ++i) {
      const int co = cog * 16 + i;
      const float* wp = &w1[(co * 32 + ci) * 9];  // wave-uniform -> s_load
      float a = acc[i];
#pragma unroll
      for (int k = 0; k < 9; ++k) a = fmaf(xv[k / 3][k % 3], wp[k], a);
      acc[i] = a;
      asc[i] = fmaf(xv[1][1], scw[co * 32 + ci], asc[i]);
    }
  }

#pragma unroll
  for (int i = 0; i < 16; ++i) {
    const int co = cog * 16 + i;
    const int oidx = ((b * 64 + co) << 12) + (h << 6) + w;
    float v = acc[i], u = asc[i];
    g_y1f[oidx] = v;
    g_yscf[oidx] = u;
    double dv = (double)v, du = (double)u;
    double s = wave_sum64(dv), q = wave_sum64(dv * dv);
    double ss = wave_sum64(du), qq = wave_sum64(du * du);
    if (w == 0) {
      g_part[co][blockIdx.x] = s;        g_part[64 + co][blockIdx.x] = q;
      g_part[128 + co][blockIdx.x] = ss; g_part[192 + co][blockIdx.x] = qq;
    }
  }
}

// ---------------- conv2 (3x3, 64->64, no bias, f32) -------------------------
__global__ __launch_bounds__(256) void conv2_kernel(const float* __restrict__ w2)
{
  const int b = blockIdx.x >> 6, h = blockIdx.x & 63;
  const int w = threadIdx.x & 63;
  const int cog = __builtin_amdgcn_readfirstlane(threadIdx.x >> 6);
  __shared__ float xs[3][64][64];   // spike values {0,1}
  for (int i = threadIdx.x; i < 3 * 64 * 64; i += 256) {
    int kh = i >> 12, ci = (i >> 6) & 63, ww = i & 63;
    int hh = h + kh - 1;
    xs[kh][ci][ww] = ((unsigned)hh < 64u) ? g_y1f[((b * 64 + ci) << 12) + (hh << 6) + ww] : 0.f;
  }
  __syncthreads();

  float acc[16];
#pragma unroll
  for (int i = 0; i < 16; ++i) acc[i] = 0.f;

  for (int ci = 0; ci < 64; ++ci) {
    float xv[3][3];
#pragma unroll
    for (int kh = 0; kh < 3; ++kh) {
      xv[kh][0] = (w > 0)  ? xs[kh][ci][w - 1] : 0.f;
      xv[kh][1] = xs[kh][ci][w];
      xv[kh][2] = (w < 63) ? xs[kh][ci][w + 1] : 0.f;
    }
#pragma unroll
    for (int i = 0; i < 16; ++i) {
      const int co = cog * 16 + i;
      const float* wp = &w2[(co * 64 + ci) * 9];
      float a = acc[i];
#pragma unroll
      for (int k = 0; k < 9; ++k) a = fmaf(xv[k / 3][k % 3], wp[k], a);
      acc[i] = a;
    }
  }

#pragma unroll
  for (int i = 0; i < 16; ++i) {
    const int co = cog * 16 + i;
    float v = acc[i];
    g_y2f[((b * 64 + co) << 12) + (h << 6) + w] = v;
    double dv = (double)v;
    double s = wave_sum64(dv), q = wave_sum64(dv * dv);
    if (w == 0) { g_part[256 + co][blockIdx.x] = s; g_part[320 + co][blockIdx.x] = q; }
  }
}

// ---------------- deterministic stat reduction ------------------------------
__global__ __launch_bounds__(256) void reduce_stats(int base)
{
  const int row = base + blockIdx.x;
  const int t = threadIdx.x;
  double s = g_part[row][t] + g_part[row][t + 256] + g_part[row][t + 512] + g_part[row][t + 768];
  s = wave_sum64(s);
  __shared__ double ls[4];
  if ((t & 63) == 0) ls[t >> 6] = s;
  __syncthreads();
  if (t == 0) g_stats[row] = ls[0] + ls[1] + ls[2] + ls[3];
}

// ---------------- BN params: scale = g*rstd, shift = b - m*scale ------------
__global__ void bn_params(int s_off, int q_off, int p_off,
                          const float* __restrict__ g, const float* __restrict__ bta)
{
  int c = threadIdx.x;
  const double inv = 1.0 / 65536.0;
  double m = g_stats[s_off + c] * inv;
  double v = g_stats[q_off + c] * inv - m * m;
  double rstd = 1.0 / sqrt(v + 1e-5);
  double sc = (double)g[c] * rstd;
  g_prm[p_off + c] = sc;
  g_prm[p_off + 64 + c] = (double)bta[c] - m * sc;
}

// ---------------- ODE (dopri5, 5 steps, f32) + spike [+ residual] -----------
// 4 rows per wave in lockstep; weights streamed from LDS (read once, used
// 4 rows x 2 matrices); x broadcast via v_readlane -> SGPR (no LDS traffic).
template <bool RES>
__global__ __launch_bounds__(256, 4) void ode_kernel(
    int prm_off, const float* __restrict__ wodep, const float* __restrict__ wtgp,
    const float* __restrict__ tgbp, float thr, float* __restrict__ outf)
{
  __shared__ float wosl[4096];
  __shared__ float wtsl[4096];
  for (int t = threadIdx.x; t < 4096; t += 256) {
    wosl[t] = wodep[t];                           // w_ode row-major
    wtsl[t] = wtgp[(t & 63) * 64 + (t >> 6)];     // wtsl[i*64+j] = tg_w[j][i]
  }
  __syncthreads();

  const int lane = threadIdx.x & 63;
  const int wv = __builtin_amdgcn_readfirstlane(threadIdx.x >> 6);
  const float tb = tgbp[lane];

  // 4 consecutive rows (same b,c; consecutive h) per wave
  const int base = blockIdx.x * 16 + wv * 4;
  const int c = (base >> 6) & 63;
  const double psc = g_prm[prm_off + c], psh = g_prm[prm_off + 64 + c];

  auto feval4 = [&](const float* xs, float* kout) {
    __builtin_amdgcn_sched_barrier(0);   // fence cross-feval motion
    float ao[4] = {0.f, 0.f, 0.f, 0.f};
    float at4[4] = {0.f, 0.f, 0.f, 0.f};
#pragma unroll 1
    for (int q = 0; q < 16; ++q) {       // runtime q: loop NOT unrolled
#pragma unroll
      for (int u = 0; u < 4; ++u) {
        const int li = q * 4 + u;        // wave-uniform -> SGPR lane index
        const float wov = wosl[li * 64 + lane];  // weight read once...
        const float wtv = wtsl[li * 64 + lane];
#pragma unroll
        for (int r = 0; r < 4; ++r) {    // ...feeds 4 rows x 2 FMAs
          const float xu = bcast_f(xs[r], li);   // v_readlane -> SGPR
          ao[r]  = fmaf(xu, wov, ao[r]);
          at4[r] = fmaf(xu, wtv, at4[r]);
        }
      }
    }
#pragma unroll
    for (int r = 0; r < 4; ++r) {
      float z = at4[r] + tb;
      float g = 0.5f * ao[r] * (1.f + erff(ao[r] * 0.70710678118654752440f));
      float e = expf(-z);
      kout[r] = g * (1.f - 1.f / (2.f + e));  // gelu * (1+e)/(2+e)
    }
  };

  const float H = (float)(1.0 / 5.0);
  const float A21 = (float)(1.0 / 5.0);
  const float A31 = (float)(3.0 / 40.0), A32 = (float)(9.0 / 40.0);
  const float A41 = (float)(44.0 / 45.0), A42 = (float)(-56.0 / 15.0), A43 = (float)(32.0 / 9.0);
  const float A51 = (float)(19372.0 / 6561.0), A52 = (float)(-25360.0 / 2187.0),
              A53 = (float)(64448.0 / 6561.0), A54 = (float)(-212.0 / 729.0);
  const float A61 = (float)(9017.0 / 3168.0), A62 = (float)(-355.0 / 33.0),
              A63 = (float)(46732.0 / 5247.0), A64 = (float)(49.0 / 176.0),
              A65 = (float)(-5103.0 / 18656.0);
  const float B1 = (float)(35.0 / 384.0), B3 = (float)(500.0 / 1113.0),
              B4 = (float)(125.0 / 192.0), B5 = (float)(-2187.0 / 6784.0),
              B6 = (float)(11.0 / 84.0);

  float xv[4];
#pragma unroll
  for (int r = 0; r < 4; ++r) {
    const int idx = ((base + r) << 6) + lane;
    const float yv = RES ? g_y2f[idx] : g_y1f[idx];
    xv[r] = (float)fma((double)yv, psc, psh);   // exact BN transform
  }

#pragma unroll 1
  for (int st5 = 0; st5 < 5; ++st5) {
    float k1[4], k2[4], k3[4], k4[4], k5[4], k6[4], tmp[4];
    feval4(xv, k1);
#pragma unroll
    for (int r = 0; r < 4; ++r) tmp[r] = xv[r] + H * (A21 * k1[r]);
    feval4(tmp, k2);
#pragma unroll
    for (int r = 0; r < 4; ++r) tmp[r] = xv[r] + H * (A31 * k1[r] + A32 * k2[r]);
    feval4(tmp, k3);
#pragma unroll
    for (int r = 0; r < 4; ++r) tmp[r] = xv[r] + H * (A41 * k1[r] + A42 * k2[r] + A43 * k3[r]);
    feval4(tmp, k4);
#pragma unroll
    for (int r = 0; r < 4; ++r)
      tmp[r] = xv[r] + H * (A51 * k1[r] + A52 * k2[r] + A53 * k3[r] + A54 * k4[r]);
    feval4(tmp, k5);
#pragma unroll
    for (int r = 0; r < 4; ++r)
      tmp[r] = xv[r] + H * (A61 * k1[r] + A62 * k2[r] + A63 * k3[r] + A64 * k4[r] + A65 * k5[r]);
    feval4(tmp, k6);
#pragma unroll
    for (int r = 0; r < 4; ++r)
      xv[r] = xv[r] + H * (B1 * k1[r] + B3 * k3[r] + B4 * k4[r] + B5 * k5[r] + B6 * k6[r]);
  }

#pragma unroll
  for (int r = 0; r < 4; ++r) {
    const int idx = ((base + r) << 6) + lane;
    float o = (xv[r] - thr > 0.f) ? 1.f : 0.f;
    if (RES) {
      double res = fma((double)g_yscf[idx], g_prm[128 + c], g_prm[192 + c]);
      outf[idx] = (float)((double)o + res);
    } else {
      g_y1f[idx] = o;   // in-place spike, exact {0,1}
    }
  }
}

// ---------------- launch ----------------------------------------------------
extern "C" void kernel_launch(void* const* d_in, const int* in_sizes, int n_in,
                              void* d_out, int out_size, void* d_ws, size_t ws_size,
                              hipStream_t stream)
{
  const float* x    = (const float*)d_in[0];
  const float* c1w  = (const float*)d_in[1];
  const float* c1b  = (const float*)d_in[2];
  const float* bn1g = (const float*)d_in[3];
  const float* bn1b = (const float*)d_in[4];
  const float* o1w  = (const float*)d_in[5];
  const float* t1w  = (const float*)d_in[6];
  const float* t1b  = (const float*)d_in[7];
  const float* c2w  = (const float*)d_in[8];
  const float* bn2g = (const float*)d_in[9];
  const float* bn2b = (const float*)d_in[10];
  const float* o2w  = (const float*)d_in[11];
  const float* t2w  = (const float*)d_in[12];
  const float* t2b  = (const float*)d_in[13];
  const float* scw  = (const float*)d_in[14];
  const float* scg  = (const float*)d_in[15];
  const float* scb  = (const float*)d_in[16];

  conv1_sc_kernel<<<1024, 256, 0, stream>>>(x, c1w, c1b, scw);
  reduce_stats<<<256, 256, 0, stream>>>(0);
  bn_params<<<1, 64, 0, stream>>>(0, 64, 0, bn1g, bn1b);
  bn_params<<<1, 64, 0, stream>>>(128, 192, 128, scg, scb);

  ode_kernel<false><<<4096, 256, 0, stream>>>(0, o1w, t1w, t1b, 0.3f, nullptr);

  conv2_kernel<<<1024, 256, 0, stream>>>(c2w);
  reduce_stats<<<128, 256, 0, stream>>>(256);
  bn_params<<<1, 64, 0, stream>>>(256, 320, 256, bn2g, bn2b);

  ode_kernel<true><<<4096, 256, 0, stream>>>(256, o2w, t2w, t2b, 0.5f, (float*)d_out);
}

// Round 13
// 1666.284 us; speedup vs baseline: 1.3660x; 1.3660x over previous
//
#include <hip/hip_runtime.h>
#include <math.h>

// ---------------------------------------------------------------------------
// R13: R12 (readlane bcast) regressed 765->1020us: readlane is ~3x modeled
// cost (SGPR hazards) and serializes into the FMA stream. R11 re-audit:
// LDS-DATA-bound: 800cy/CU-feval4 (x b128 bcast 512 + weights 256) -> 640us
// ~= 84% of 765 measured. x-bcast (128cy/row-feval) is irreducible here;
// weights (256/R) amortize with rows/wave. R13 = R11 structure with R=8:
// LDS ~1300cy/CU-feval8 -> ~520us floor, VALU ~320us -> LDS-bound ~520-600.
// Convs/BN unchanged (pass, absmax 0.03125).
// ---------------------------------------------------------------------------

#define NELEM (16 * 64 * 64 * 64)  // 4194304, B*C*H*W with C=64

__device__ float  g_y1f[NELEM];   // conv1 out -> overwritten in-place by spike1
__device__ float  g_yscf[NELEM];  // 1x1 shortcut conv out
__device__ float  g_y2f[NELEM];   // conv2 out
__device__ double g_part[384][1024];  // per-block stat partials (f64)
__device__ double g_stats[384];
__device__ double g_prm[384];     // [0]=bn1 sc,[64]=bn1 sh,[128]=sc sc,[192]=sc sh,
                                  // [256]=bn2 sc,[320]=bn2 sh

__device__ __forceinline__ double wave_sum64(double v) {
#pragma unroll
  for (int m = 1; m < 64; m <<= 1) v += __shfl_xor(v, m);
  return v;
}

// ---------------- conv1 (3x3, 32->64, bias, f32) + sc conv (1x1) ------------
__global__ __launch_bounds__(256) void conv1_sc_kernel(
    const float* __restrict__ x, const float* __restrict__ w1,
    const float* __restrict__ b1, const float* __restrict__ scw)
{
  const int b = blockIdx.x >> 6, h = blockIdx.x & 63;
  const int w = threadIdx.x & 63;
  const int cog = __builtin_amdgcn_readfirstlane(threadIdx.x >> 6);  // 0..3
  __shared__ float xs[3][32][64];
  for (int i = threadIdx.x; i < 3 * 32 * 64; i += 256) {
    int kh = i >> 11, ci = (i >> 6) & 31, ww = i & 63;
    int hh = h + kh - 1;
    xs[kh][ci][ww] = ((unsigned)hh < 64u) ? x[((b * 32 + ci) << 12) + (hh << 6) + ww] : 0.f;
  }
  __syncthreads();

  float acc[16], asc[16];
#pragma unroll
  for (int i = 0; i < 16; ++i) { acc[i] = b1[cog * 16 + i]; asc[i] = 0.f; }

  for (int ci = 0; ci < 32; ++ci) {
    float xv[3][3];
#pragma unroll
    for (int kh = 0; kh < 3; ++kh) {
      xv[kh][0] = (w > 0)  ? xs[kh][ci][w - 1] : 0.f;
      xv[kh][1] = xs[kh][ci][w];
      xv[kh][2] = (w < 63) ? xs[kh][ci][w + 1] : 0.f;
    }
#pragma unroll
    for (int i = 0; i < 16; ++i) {
      const int co = cog * 16 + i;
      const float* wp = &w1[(co * 32 + ci) * 9];  // wave-uniform -> s_load
      float a = acc[i];
#pragma unroll
      for (int k = 0; k < 9; ++k) a = fmaf(xv[k / 3][k % 3], wp[k], a);
      acc[i] = a;
      asc[i] = fmaf(xv[1][1], scw[co * 32 + ci], asc[i]);
    }
  }

#pragma unroll
  for (int i = 0; i < 16; ++i) {
    const int co = cog * 16 + i;
    const int oidx = ((b * 64 + co) << 12) + (h << 6) + w;
    float v = acc[i], u = asc[i];
    g_y1f[oidx] = v;
    g_yscf[oidx] = u;
    double dv = (double)v, du = (double)u;
    double s = wave_sum64(dv), q = wave_sum64(dv * dv);
    double ss = wave_sum64(du), qq = wave_sum64(du * du);
    if (w == 0) {
      g_part[co][blockIdx.x] = s;        g_part[64 + co][blockIdx.x] = q;
      g_part[128 + co][blockIdx.x] = ss; g_part[192 + co][blockIdx.x] = qq;
    }
  }
}

// ---------------- conv2 (3x3, 64->64, no bias, f32) -------------------------
__global__ __launch_bounds__(256) void conv2_kernel(const float* __restrict__ w2)
{
  const int b = blockIdx.x >> 6, h = blockIdx.x & 63;
  const int w = threadIdx.x & 63;
  const int cog = __builtin_amdgcn_readfirstlane(threadIdx.x >> 6);
  __shared__ float xs[3][64][64];   // spike values {0,1}
  for (int i = threadIdx.x; i < 3 * 64 * 64; i += 256) {
    int kh = i >> 12, ci = (i >> 6) & 63, ww = i & 63;
    int hh = h + kh - 1;
    xs[kh][ci][ww] = ((unsigned)hh < 64u) ? g_y1f[((b * 64 + ci) << 12) + (hh << 6) + ww] : 0.f;
  }
  __syncthreads();

  float acc[16];
#pragma unroll
  for (int i = 0; i < 16; ++i) acc[i] = 0.f;

  for (int ci = 0; ci < 64; ++ci) {
    float xv[3][3];
#pragma unroll
    for (int kh = 0; kh < 3; ++kh) {
      xv[kh][0] = (w > 0)  ? xs[kh][ci][w - 1] : 0.f;
      xv[kh][1] = xs[kh][ci][w];
      xv[kh][2] = (w < 63) ? xs[kh][ci][w + 1] : 0.f;
    }
#pragma unroll
    for (int i = 0; i < 16; ++i) {
      const int co = cog * 16 + i;
      const float* wp = &w2[(co * 64 + ci) * 9];
      float a = acc[i];
#pragma unroll
      for (int k = 0; k < 9; ++k) a = fmaf(xv[k / 3][k % 3], wp[k], a);
      acc[i] = a;
    }
  }

#pragma unroll
  for (int i = 0; i < 16; ++i) {
    const int co = cog * 16 + i;
    float v = acc[i];
    g_y2f[((b * 64 + co) << 12) + (h << 6) + w] = v;
    double dv = (double)v;
    double s = wave_sum64(dv), q = wave_sum64(dv * dv);
    if (w == 0) { g_part[256 + co][blockIdx.x] = s; g_part[320 + co][blockIdx.x] = q; }
  }
}

// ---------------- deterministic stat reduction ------------------------------
__global__ __launch_bounds__(256) void reduce_stats(int base)
{
  const int row = base + blockIdx.x;
  const int t = threadIdx.x;
  double s = g_part[row][t] + g_part[row][t + 256] + g_part[row][t + 512] + g_part[row][t + 768];
  s = wave_sum64(s);
  __shared__ double ls[4];
  if ((t & 63) == 0) ls[t >> 6] = s;
  __syncthreads();
  if (t == 0) g_stats[row] = ls[0] + ls[1] + ls[2] + ls[3];
}

// ---------------- BN params: scale = g*rstd, shift = b - m*scale ------------
__global__ void bn_params(int s_off, int q_off, int p_off,
                          const float* __restrict__ g, const float* __restrict__ bta)
{
  int c = threadIdx.x;
  const double inv = 1.0 / 65536.0;
  double m = g_stats[s_off + c] * inv;
  double v = g_stats[q_off + c] * inv - m * m;
  double rstd = 1.0 / sqrt(v + 1e-5);
  double sc = (double)g[c] * rstd;
  g_prm[p_off + c] = sc;
  g_prm[p_off + 64 + c] = (double)bta[c] - m * sc;
}

// ---------------- ODE (dopri5, 5 steps, f32) + spike [+ residual] -----------
// R13: 8 rows per wave in LOCKSTEP. Each weight dword read once from LDS
// feeds 8 rows x 2 matrices (16 FMAs); x broadcast via same-address b128
// (BW-optimal: 2cy/float, 4 floats/inst).
template <bool RES>
__global__ __launch_bounds__(256, 3) void ode_kernel(
    int prm_off, const float* __restrict__ wodep, const float* __restrict__ wtgp,
    const float* __restrict__ tgbp, float thr, float* __restrict__ outf)
{
  __shared__ float wosl[4096];
  __shared__ float wtsl[4096];
  __shared__ __align__(16) float xbuf[4][8][64];   // [wave][row][elem] = 8KB
  for (int t = threadIdx.x; t < 4096; t += 256) {
    wosl[t] = wodep[t];                           // w_ode row-major
    wtsl[t] = wtgp[(t & 63) * 64 + (t >> 6)];     // wtsl[i*64+j] = tg_w[j][i]
  }
  __syncthreads();

  const int lane = threadIdx.x & 63;
  const int wv = __builtin_amdgcn_readfirstlane(threadIdx.x >> 6);
  const float tb = tgbp[lane];
  float* __restrict__ xrow = &xbuf[wv][0][0];     // [r*64 + lane]

  // 8 consecutive rows (same b,c; consecutive h) per wave
  const int base = blockIdx.x * 32 + wv * 8;
  const int c = (base >> 6) & 63;
  const double psc = g_prm[prm_off + c], psh = g_prm[prm_off + 64 + c];

  auto feval8 = [&](const float* xs, float* kout) {
    __builtin_amdgcn_sched_barrier(0);   // fence cross-feval motion
#pragma unroll
    for (int r = 0; r < 8; ++r) xrow[r * 64 + lane] = xs[r];  // 8x ds_write_b32
    float ao[8], at8[8];
#pragma unroll
    for (int r = 0; r < 8; ++r) { ao[r] = 0.f; at8[r] = 0.f; }
#pragma unroll 1
    for (int q = 0; q < 16; ++q) {       // runtime q: loop NOT unrolled
      float4 xq[8];
#pragma unroll
      for (int r = 0; r < 8; ++r)        // same-addr broadcast b128 reads
        xq[r] = *reinterpret_cast<const float4*>(&xrow[r * 64 + q * 4]);
#pragma unroll
      for (int u = 0; u < 4; ++u) {
        const float wov = wosl[(q * 4 + u) * 64 + lane];  // read once...
        const float wtv = wtsl[(q * 4 + u) * 64 + lane];
#pragma unroll
        for (int r = 0; r < 8; ++r) {    // ...feeds 8 rows x 2 FMAs
          const float xu = (&xq[r].x)[u];   // u,r unrolled -> static index
          ao[r]  = fmaf(xu, wov, ao[r]);
          at8[r] = fmaf(xu, wtv, at8[r]);
        }
      }
    }
#pragma unroll
    for (int r = 0; r < 8; ++r) {
      float z = at8[r] + tb;
      float g = 0.5f * ao[r] * (1.f + erff(ao[r] * 0.70710678118654752440f));
      float e = expf(-z);
      kout[r] = g * (1.f - 1.f / (2.f + e));  // gelu * (1+e)/(2+e)
    }
  };

  const float H = (float)(1.0 / 5.0);
  const float A21 = (float)(1.0 / 5.0);
  const float A31 = (float)(3.0 / 40.0), A32 = (float)(9.0 / 40.0);
  const float A41 = (float)(44.0 / 45.0), A42 = (float)(-56.0 / 15.0), A43 = (float)(32.0 / 9.0);
  const float A51 = (float)(19372.0 / 6561.0), A52 = (float)(-25360.0 / 2187.0),
              A53 = (float)(64448.0 / 6561.0), A54 = (float)(-212.0 / 729.0);
  const float A61 = (float)(9017.0 / 3168.0), A62 = (float)(-355.0 / 33.0),
              A63 = (float)(46732.0 / 5247.0), A64 = (float)(49.0 / 176.0),
              A65 = (float)(-5103.0 / 18656.0);
  const float B1 = (float)(35.0 / 384.0), B3 = (float)(500.0 / 1113.0),
              B4 = (float)(125.0 / 192.0), B5 = (float)(-2187.0 / 6784.0),
              B6 = (float)(11.0 / 84.0);

  float xv[8];
#pragma unroll
  for (int r = 0; r < 8; ++r) {
    const int idx = ((base + r) << 6) + lane;
    const float yv = RES ? g_y2f[idx] : g_y1f[idx];
    xv[r] = (float)fma((double)yv, psc, psh);   // exact BN transform
  }

#pragma unroll 1
  for (int st5 = 0; st5 < 5; ++st5) {
    float k1[8], k2[8], k3[8], k4[8], k5[8], k6[8], tmp[8];
    feval8(xv, k1);
#pragma unroll
    for (int r = 0; r < 8; ++r) tmp[r] = xv[r] + H * (A21 * k1[r]);
    feval8(tmp, k2);
#pragma unroll
    for (int r = 0; r < 8; ++r) tmp[r] = xv[r] + H * (A31 * k1[r] + A32 * k2[r]);
    feval8(tmp, k3);
#pragma unroll
    for (int r = 0; r < 8; ++r) tmp[r] = xv[r] + H * (A41 * k1[r] + A42 * k2[r] + A43 * k3[r]);
    feval8(tmp, k4);
#pragma unroll
    for (int r = 0; r < 8; ++r)
      tmp[r] = xv[r] + H * (A51 * k1[r] + A52 * k2[r] + A53 * k3[r] + A54 * k4[r]);
    feval8(tmp, k5);
#pragma unroll
    for (int r = 0; r < 8; ++r)
      tmp[r] = xv[r] + H * (A61 * k1[r] + A62 * k2[r] + A63 * k3[r] + A64 * k4[r] + A65 * k5[r]);
    feval8(tmp, k6);
#pragma unroll
    for (int r = 0; r < 8; ++r)
      xv[r] = xv[r] + H * (B1 * k1[r] + B3 * k3[r] + B4 * k4[r] + B5 * k5[r] + B6 * k6[r]);
  }

#pragma unroll
  for (int r = 0; r < 8; ++r) {
    const int idx = ((base + r) << 6) + lane;
    float o = (xv[r] - thr > 0.f) ? 1.f : 0.f;
    if (RES) {
      double res = fma((double)g_yscf[idx], g_prm[128 + c], g_prm[192 + c]);
      outf[idx] = (float)((double)o + res);
    } else {
      g_y1f[idx] = o;   // in-place spike, exact {0,1}
    }
  }
}

// ---------------- launch ----------------------------------------------------
extern "C" void kernel_launch(void* const* d_in, const int* in_sizes, int n_in,
                              void* d_out, int out_size, void* d_ws, size_t ws_size,
                              hipStream_t stream)
{
  const float* x    = (const float*)d_in[0];
  const float* c1w  = (const float*)d_in[1];
  const float* c1b  = (const float*)d_in[2];
  const float* bn1g = (const float*)d_in[3];
  const float* bn1b = (const float*)d_in[4];
  const float* o1w  = (const float*)d_in[5];
  const float* t1w  = (const float*)d_in[6];
  const float* t1b  = (const float*)d_in[7];
  const float* c2w  = (const float*)d_in[8];
  const float* bn2g = (const float*)d_in[9];
  const float* bn2b = (const float*)d_in[10];
  const float* o2w  = (const float*)d_in[11];
  const float* t2w  = (const float*)d_in[12];
  const float* t2b  = (const float*)d_in[13];
  const float* scw  = (const float*)d_in[14];
  const float* scg  = (const float*)d_in[15];
  const float* scb  = (const float*)d_in[16];

  conv1_sc_kernel<<<1024, 256, 0, stream>>>(x, c1w, c1b, scw);
  reduce_stats<<<256, 256, 0, stream>>>(0);
  bn_params<<<1, 64, 0, stream>>>(0, 64, 0, bn1g, bn1b);
  bn_params<<<1, 64, 0, stream>>>(128, 192, 128, scg, scb);

  ode_kernel<false><<<2048, 256, 0, stream>>>(0, o1w, t1w, t1b, 0.3f, nullptr);

  conv2_kernel<<<1024, 256, 0, stream>>>(c2w);
  reduce_stats<<<128, 256, 0, stream>>>(256);
  bn_params<<<1, 64, 0, stream>>>(256, 320, 256, bn2g, bn2b);

  ode_kernel<true><<<2048, 256, 0, stream>>>(256, o2w, t2w, t2b, 0.5f, (float*)d_out);
}